// Round 13
// baseline (129.866 us; speedup 1.0000x reference)
//
#include <hip/hip_runtime.h>
#include <cstdint>
#include <cstddef>

#define B_   8
#define S_   1024
#define H_   1024
#define NH_  16
#define HD_  64
#define M_   8192   // B*S
#define N3_  3072   // 3*H
#define K_   1024

typedef __attribute__((ext_vector_type(8))) short bf16x8;
typedef __attribute__((ext_vector_type(4))) float f32x4;
typedef __attribute__((ext_vector_type(16))) float f32x16;
typedef __attribute__((ext_vector_type(8))) unsigned short u16x8;
typedef __attribute__((ext_vector_type(4))) unsigned u32x4;

__device__ __forceinline__ unsigned short f2bf(float f) {
  unsigned u = __builtin_bit_cast(unsigned, f);
  u += 0x7fffu + ((u >> 16) & 1u);      // round-to-nearest-even (finite inputs)
  return (unsigned short)(u >> 16);
}

__device__ __forceinline__ unsigned long long pack4bf(float a, float b,
                                                      float c, float d) {
  return (unsigned long long)f2bf(a)
       | ((unsigned long long)f2bf(b) << 16)
       | ((unsigned long long)f2bf(c) << 32)
       | ((unsigned long long)f2bf(d) << 48);
}

// one-instruction bf16-pair pack (RNE), T12 recipe
__device__ __forceinline__ unsigned cvtpk(float a, float b) {
  unsigned r;
  asm("v_cvt_pk_bf16_f32 %0, %1, %2" : "=v"(r) : "v"(a), "v"(b));
  return r;
}

// ---------------- fp32 -> bf16 pack ----------------
__global__ void cvt_kernel(const float* __restrict__ src,
                           unsigned short* __restrict__ dst, int n) {
  const int stride = gridDim.x * blockDim.x * 8;
  for (int i = (blockIdx.x * blockDim.x + threadIdx.x) * 8; i < n; i += stride) {
    float4 a = *reinterpret_cast<const float4*>(src + i);
    float4 b = *reinterpret_cast<const float4*>(src + i + 4);
    u16x8 o;
    o[0] = f2bf(a.x); o[1] = f2bf(a.y); o[2] = f2bf(a.z); o[3] = f2bf(a.w);
    o[4] = f2bf(b.x); o[5] = f2bf(b.y); o[6] = f2bf(b.z); o[7] = f2bf(b.w);
    *reinterpret_cast<u16x8*>(dst + i) = o;
  }
}

// fused q/k/v weight cvt (one launch): dst = [qw|kw|vw] bf16
__global__ void wcvt_kernel(const float* __restrict__ q,
                            const float* __restrict__ k,
                            const float* __restrict__ v,
                            unsigned short* __restrict__ dst) {
  const int i = (blockIdx.x * blockDim.x + threadIdx.x) * 8;   // < 3M
  const float* src;
  int off;
  if (i < 1048576)      { src = q; off = i; }
  else if (i < 2097152) { src = k; off = i - 1048576; }
  else                  { src = v; off = i - 2097152; }
  float4 a = *reinterpret_cast<const float4*>(src + off);
  float4 b = *reinterpret_cast<const float4*>(src + off + 4);
  u16x8 o;
  o[0] = f2bf(a.x); o[1] = f2bf(a.y); o[2] = f2bf(a.z); o[3] = f2bf(a.w);
  o[4] = f2bf(b.x); o[5] = f2bf(b.y); o[6] = f2bf(b.z); o[7] = f2bf(b.w);
  *reinterpret_cast<u16x8*>(dst + i) = o;
}

// ------- fused QKV GEMM: 256x128, BK=64, 2-phase/K-tile counted-vmcnt ring ---
// 512 thr = 8 waves (4M x 2N), 64x64/wave (acc = round-9's proven 16 f32x4).
// LDS ring: 3 x (A 32K | B 16K) = 144KB, 1 block/CU, grid 768 = 3 clean rounds.
// Per K-tile: P1 {ds_read kk=0 || stage A0,A1(kt+2)} barrier MFMA barrier;
//             P2 {ds_read kk=1 || stage B(kt+2), vmcnt(6)} barrier MFMA barrier.
// Loads stay in flight across barriers (raw s_barrier, no drain) - T3+T4.
__global__ __launch_bounds__(512, 1) void qkv_gemm(
    const unsigned short* __restrict__ A,    // [8192][1024] bf16
    const unsigned short* __restrict__ Bw,   // [3072][1024] bf16 (qw|kw|vw rows)
    const float* __restrict__ qb, const float* __restrict__ kb,
    const float* __restrict__ vb,
    unsigned short* __restrict__ Qh,   // [128][1024][64], pre-scaled by log2e/32
    unsigned short* __restrict__ Kh,   // [128][1024][64]
    unsigned short* __restrict__ Vth)  // [128][16 kt][64 hd][64 k]
{
  extern __shared__ char sm[];            // 3 x 48KB ring (A 32K | B 16K)
  const int t = threadIdx.x;              // 0..511
  const int lane = t & 63;
  const int wave = t >> 6;
  const int wm = wave >> 1;               // 0..3 (64-row strip of 256)
  const int wn = wave & 1;                // 0..1 (64-col strip of 128)

  // L2 supertile (round-12 verified): per XCD, A 4bm x 512KB = 2MB + B 8bn
  // x 256KB = 2MB = 4MB = one L2.
  const int bid = blockIdx.x;             // 0..767
  const int c = bid >> 3;                 // 0..95
  const int g = c >> 5;                   // 0..2  (tensor group)
  const int m = (c >> 3) & 3;             // 0..3
  const int n = c & 7;                    // 0..7
  const int bm = (bid & 7) * 4 + m;       // 0..31 (256-row tiles)
  const int bn = g * 8 + n;               // 0..23 (128-col tiles)

  const char* Ab = (const char*)A + (size_t)bm * 256 * 2048;
  const char* Bb = (const char*)Bw + (size_t)bn * 128 * 2048;

  f32x4 acc[4][4] = {};

  // stage A half h (16KB, rows h*128..+127) of K-slice kt into ring buf q
  #define STGA(kt, q, h)                                                       \
    { char* Ld = sm + (q) * 49152 + (h) * 16384;                               \
      _Pragma("unroll")                                                        \
      for (int j = 0; j < 2; ++j) {                                            \
        const int off = j * 8192 + t * 16;                                     \
        const int row = (h) * 128 + (off >> 7);                                \
        const int sc  = ((off >> 4) & 7) ^ (row & 7);                          \
        __builtin_amdgcn_global_load_lds(                                      \
          (const __attribute__((address_space(1))) void*)(Ab + (size_t)row * 2048 + (kt) * 128 + sc * 16), \
          (__attribute__((address_space(3))) void*)(Ld + off), 16, 0, 0);      \
      } }
  // stage B (16KB, 128 rows) of K-slice kt into ring buf q
  #define STGB(kt, q)                                                          \
    { char* Ld = sm + (q) * 49152 + 32768;                                     \
      _Pragma("unroll")                                                        \
      for (int j = 0; j < 2; ++j) {                                            \
        const int off = j * 8192 + t * 16;                                     \
        const int row = off >> 7;                                              \
        const int sc  = ((off >> 4) & 7) ^ (row & 7);                          \
        __builtin_amdgcn_global_load_lds(                                      \
          (const __attribute__((address_space(1))) void*)(Bb + (size_t)row * 2048 + (kt) * 128 + sc * 16), \
          (__attribute__((address_space(3))) void*)(Ld + off), 16, 0, 0);      \
      } }

  #define VM6 asm volatile("s_waitcnt vmcnt(6)" ::: "memory")
  #define VM0 asm volatile("s_waitcnt vmcnt(0)" ::: "memory")
  #define BARR asm volatile("s_barrier" ::: "memory")

  // one compute phase: 8 ds_read_b128 + 16 MFMA at K sub-step kk
  #define PH_READS(KK)                                                         \
    bf16x8 af[4], bf[4];                                                       \
    _Pragma("unroll")                                                          \
    for (int mb = 0; mb < 4; ++mb) {                                           \
      const int row = wm * 64 + mb * 16 + (lane & 15);                         \
      af[mb] = *(const bf16x8*)(Acur + row * 128 +                             \
                ((((KK) * 4 + (lane >> 4)) ^ (row & 7)) << 4));                \
    }                                                                          \
    _Pragma("unroll")                                                          \
    for (int nb = 0; nb < 4; ++nb) {                                           \
      const int row = wn * 64 + nb * 16 + (lane & 15);                         \
      bf[nb] = *(const bf16x8*)(Bcur + row * 128 +                             \
                ((((KK) * 4 + (lane >> 4)) ^ (row & 7)) << 4));                \
    }
  #define PH_MFMA                                                              \
    __builtin_amdgcn_s_setprio(1);                                             \
    _Pragma("unroll")                                                          \
    for (int mb = 0; mb < 4; ++mb)                                             \
      _Pragma("unroll")                                                        \
      for (int nb = 0; nb < 4; ++nb)                                           \
        acc[mb][nb] = __builtin_amdgcn_mfma_f32_16x16x32_bf16(                 \
            af[mb], bf[nb], acc[mb][nb], 0, 0, 0);                             \
    __builtin_amdgcn_s_setprio(0);

  // prologue: tiles 0,1 fully issued (12 loads); confirm tile 0 (6 stay flying)
  STGA(0, 0, 0) STGA(0, 0, 1) STGB(0, 0)
  STGA(1, 1, 0) STGA(1, 1, 1) STGB(1, 1)
  VM6;
  BARR;

  for (int kt = 0; kt < 16; ++kt) {
    const char* Acur = sm + (kt % 3) * 49152;
    const char* Bcur = Acur + 32768;
    const int qn = (kt + 2) % 3;
    // ---- P1: kk=0 ----
    {
      PH_READS(0)
      if (kt < 14) { STGA(kt + 2, qn, 0) STGA(kt + 2, qn, 1) }
      BARR;
      PH_MFMA
      BARR;
    }
    // ---- P2: kk=1 ----
    {
      PH_READS(1)
      if (kt < 14) { STGB(kt + 2, qn) VM6; }
      else if (kt == 14) VM0;
      BARR;
      PH_MFMA
      BARR;
    }
  }
  __syncthreads();   // full drain before LDS reuse by epilogue

  // ---------------- coalesced epilogue through LDS (E = 64KB of sm) --------
  const int tensor = bn >> 3;             // block-uniform: 0=q 1=k 2=v
  const float scl = (tensor == 0) ? 0.04508422f : 1.0f;  // log2e/sqrt(1024)
  const float* bias = (tensor == 0) ? qb : (tensor == 1) ? kb : vb;
  char* E = sm;
  const int bloc = bm >> 2;               // batch b (0..7)
  const int srow = (bm & 3) * 256;        // s base of tile

  if (tensor < 2) {
    // row-major [row 256][col 128] bf16 (256B rows), chunk-swizzled
    #pragma unroll
    for (int nb = 0; nb < 4; ++nb) {
      const int col = wn * 64 + nb * 16 + (lane & 15);
      const float bv = bias[(bn & 7) * 128 + col];
      #pragma unroll
      for (int mb = 0; mb < 4; ++mb) {
        #pragma unroll
        for (int r = 0; r < 4; ++r) {
          const int row = wm * 64 + mb * 16 + (lane >> 4) * 4 + r;
          const int byo = row * 256 + ((((col >> 3) ^ (row & 7)) << 4) | ((col & 7) << 1));
          *(unsigned short*)(E + byo) = f2bf((acc[mb][nb][r] + bv) * scl);
        }
      }
    }
    __syncthreads();
    unsigned short* dst = (tensor == 0) ? Qh : Kh;
    #pragma unroll
    for (int cch = 0; cch < 8; ++cch) {
      const int o = t * 128 + cch * 16;
      const int row = o >> 8;             // 0..255
      const int colb = o & 255;           // byte-in-row, 16B aligned
      const int col = colb >> 1;
      u32x4 v = *(const u32x4*)(E + row * 256 + ((((colb >> 4) ^ (row & 7)) << 4)));
      const int sg = srow + row;
      const int nhh = (bn & 7) * 2 + (col >> 6);
      const size_t db = ((size_t)(bloc * NH_ + nhh) * S_ + (sg & 1023)) * 128 + (col & 63) * 2;
      *(u32x4*)((char*)dst + db) = v;
    }
  } else {
    // transposed [col 128][row 256] bf16 (512B cols); r-quads pack to b64
    #pragma unroll
    for (int nb = 0; nb < 4; ++nb) {
      const int col = wn * 64 + nb * 16 + (lane & 15);
      const float bv = bias[(bn & 7) * 128 + col];
      #pragma unroll
      for (int mb = 0; mb < 4; ++mb) {
        const int row0 = wm * 64 + mb * 16 + (lane >> 4) * 4;
        unsigned long long w = pack4bf(acc[mb][nb][0] + bv, acc[mb][nb][1] + bv,
                                       acc[mb][nb][2] + bv, acc[mb][nb][3] + bv);
        const int byo = col * 512 + ((((row0 >> 3) ^ (col & 7)) << 4) | ((row0 & 7) << 1));
        *(unsigned long long*)(E + byo) = w;
      }
    }
    __syncthreads();
    #pragma unroll
    for (int cch = 0; cch < 8; ++cch) {
      const int o = t * 128 + cch * 16;
      const int col = o >> 9;             // 0..127
      const int rowb = o & 511;           // byte-in-col, 16B aligned
      const int row0 = rowb >> 1;         // 8 consecutive rows
      u32x4 v = *(const u32x4*)(E + col * 512 + ((((rowb >> 4) ^ (col & 7)) << 4)));
      const int sg0 = srow + row0;
      const int nhh = (bn & 7) * 2 + (col >> 6);
      const size_t db = (size_t)(bloc * NH_ + nhh) * 131072 +
                        (size_t)((sg0 & 1023) >> 6) * 8192 + (col & 63) * 128 + (sg0 & 63) * 2;
      *(u32x4*)((char*)Vth + db) = v;
    }
  }
}

// ---- build PV A-frag for one 16-k step from 8 consecutive P regs ----
__device__ __forceinline__ bf16x8 mk_frag(const f32x16& s, const int base) {
  unsigned a0 = cvtpk(s[base + 0], s[base + 1]);
  unsigned a1 = cvtpk(s[base + 2], s[base + 3]);
  unsigned b0 = cvtpk(s[base + 4], s[base + 5]);
  unsigned b1 = cvtpk(s[base + 6], s[base + 7]);
  asm("v_permlane32_swap_b32 %0, %1" : "+v"(a0), "+v"(b0));
  asm("v_permlane32_swap_b32 %0, %1" : "+v"(a1), "+v"(b1));
  u32x4 u = {a0, a1, b0, b1};
  return __builtin_bit_cast(bf16x8, u);
}

// ---------------- flash attention: LDS-staged K/V, double-buffered ----------------
// (round-9 best config: 3 blocks/CU, no setprio)
__global__ __launch_bounds__(256, 3) void attn_kernel(
    const unsigned short* __restrict__ Qh,
    const unsigned short* __restrict__ Kh,
    const unsigned short* __restrict__ Vth,
    float* __restrict__ Out)
{
  __shared__ char smx[2][16384];   // [buf][ K 8KB | V 8KB ]
  const int t = threadIdx.x;
  const int lane = t & 63;
  const int wave = t >> 6;
  const int l31 = lane & 31;
  const int hi = lane >> 5;
  const int hw = blockIdx.x;              // 0..1023
  const int xcd = hw & 7;
  const int qt = (hw >> 3) & 7;
  const int bh = (hw >> 6) * 8 + xcd;     // 0..127
  const int b = bh >> 4, nh = bh & 15;

  const unsigned short* Qp = Qh + (size_t)bh * (S_ * HD_);
  const char* Kp = (const char*)Kh + (size_t)bh * 131072;
  const char* Vp = (const char*)Vth + (size_t)bh * 131072;
  const int q0 = qt * 128 + wave * 32;

  bf16x8 bq[4];
  #pragma unroll
  for (int st = 0; st < 4; ++st)
    bq[st] = *reinterpret_cast<const bf16x8*>(
        Qp + (size_t)(q0 + l31) * HD_ + st * 16 + hi * 8);

  const int soff0 = wave * 1024 + lane * 16;
  #define STAGE_TILE(dstbase, srcbase)                                            \
    _Pragma("unroll")                                                             \
    for (int j = 0; j < 2; ++j) {                                                 \
      const int off = j * 4096 + soff0;                                           \
      const int row = off >> 7;                                                   \
      const int sc  = ((off >> 4) & 7) ^ (row & 7);                               \
      __builtin_amdgcn_global_load_lds(                                           \
          (const __attribute__((address_space(1))) void*)((srcbase) + row * 128 + sc * 16), \
          (__attribute__((address_space(3))) void*)((dstbase) + off), 16, 0, 0);  \
    }

  STAGE_TILE(&smx[0][0],    Kp)
  STAGE_TILE(&smx[0][8192], Vp)
  __syncthreads();

  f32x16 o0 = {}, o1 = {};
  float lsum = 0.f;
  const int swr = l31 & 7;

  for (int kt = 0; kt < 16; ++kt) {
    const int cur = kt & 1;
    if (kt < 15) {
      STAGE_TILE(&smx[cur ^ 1][0],    Kp + (kt + 1) * 8192)
      STAGE_TILE(&smx[cur ^ 1][8192], Vp + (kt + 1) * 8192)
    }
    const char* Kb = &smx[cur][0];
    const char* Vb = &smx[cur][8192];

    f32x16 s0 = {}, s1 = {};
    #pragma unroll
    for (int st = 0; st < 4; ++st) {
      const int c = ((st * 2 + hi) ^ swr) << 4;
      bf16x8 ka = *reinterpret_cast<const bf16x8*>(Kb + l31 * 128 + c);
      bf16x8 kc = *reinterpret_cast<const bf16x8*>(Kb + (l31 + 32) * 128 + c);
      s0 = __builtin_amdgcn_mfma_f32_32x32x16_bf16(ka, bq[st], s0, 0, 0, 0);
      s1 = __builtin_amdgcn_mfma_f32_32x32x16_bf16(kc, bq[st], s1, 0, 0, 0);
    }

    bf16x8 va[4];
    #pragma unroll
    for (int ks = 0; ks < 2; ++ks) {
      const int c = ((ks * 2 + hi) ^ swr) << 4;
      va[ks * 2]     = *reinterpret_cast<const bf16x8*>(Vb + l31 * 128 + c);
      va[ks * 2 + 1] = *reinterpret_cast<const bf16x8*>(Vb + (l31 + 32) * 128 + c);
    }
    #pragma unroll
    for (int r = 0; r < 16; ++r) {
      s0[r] = __builtin_amdgcn_exp2f(s0[r]);
      lsum += s0[r];
    }
    bf16x8 f0 = mk_frag(s0, 0);
    bf16x8 f1 = mk_frag(s0, 8);
    o0 = __builtin_amdgcn_mfma_f32_32x32x16_bf16(f0, va[0], o0, 0, 0, 0);
    o1 = __builtin_amdgcn_mfma_f32_32x32x16_bf16(f0, va[1], o1, 0, 0, 0);
    o0 = __builtin_amdgcn_mfma_f32_32x32x16_bf16(f1, va[2], o0, 0, 0, 0);
    o1 = __builtin_amdgcn_mfma_f32_32x32x16_bf16(f1, va[3], o1, 0, 0, 0);

    #pragma unroll
    for (int ks = 0; ks < 2; ++ks) {
      const int c = (((ks + 2) * 2 + hi) ^ swr) << 4;
      va[ks * 2]     = *reinterpret_cast<const bf16x8*>(Vb + l31 * 128 + c);
      va[ks * 2 + 1] = *reinterpret_cast<const bf16x8*>(Vb + (l31 + 32) * 128 + c);
    }
    #pragma unroll
    for (int r = 0; r < 16; ++r) {
      s1[r] = __builtin_amdgcn_exp2f(s1[r]);
      lsum += s1[r];
    }
    bf16x8 f2 = mk_frag(s1, 0);
    bf16x8 f3 = mk_frag(s1, 8);
    o0 = __builtin_amdgcn_mfma_f32_32x32x16_bf16(f2, va[0], o0, 0, 0, 0);
    o1 = __builtin_amdgcn_mfma_f32_32x32x16_bf16(f2, va[1], o1, 0, 0, 0);
    o0 = __builtin_amdgcn_mfma_f32_32x32x16_bf16(f3, va[2], o0, 0, 0, 0);
    o1 = __builtin_amdgcn_mfma_f32_32x32x16_bf16(f3, va[3], o1, 0, 0, 0);

    __syncthreads();
  }

  const float ltot = lsum + __shfl_xor(lsum, 32);
  const float inv = 1.0f / ltot;
  #pragma unroll
  for (int r = 0; r < 16; ++r) {
    const int crow = (r & 3) + 8 * (r >> 2) + 4 * hi;
    const float invq = __shfl(inv, crow);
    float* op = Out + ((size_t)(b * S_ + q0 + crow)) * H_ + nh * HD_ + l31;
    op[0]  = o0[r] * invq;
    op[32] = o1[r] * invq;
  }
}

extern "C" void kernel_launch(void* const* d_in, const int* in_sizes, int n_in,
                              void* d_out, int out_size, void* d_ws, size_t ws_size,
                              hipStream_t stream) {
  const float* act = (const float*)d_in[0];
  const float* qw  = (const float*)d_in[1];
  const float* qb  = (const float*)d_in[2];
  const float* kw  = (const float*)d_in[3];
  const float* kb  = (const float*)d_in[4];
  const float* vw  = (const float*)d_in[5];
  const float* vb  = (const float*)d_in[6];

  char* ws = (char*)d_ws;
  unsigned short* actb = (unsigned short*)ws;                         // 16 MB
  unsigned short* wb   = (unsigned short*)(ws + 16777216);            // 6 MB
  unsigned short* Qh   = (unsigned short*)(ws + 23068672);            // 16 MB
  unsigned short* Kh   = Qh + 8388608;                                // 16 MB
  unsigned short* Vth  = Kh + 8388608;                                // 16 MB

  cvt_kernel<<<4096, 256, 0, stream>>>(act, actb, M_ * K_);
  wcvt_kernel<<<1536, 256, 0, stream>>>(qw, kw, vw, wb);

  hipFuncSetAttribute((const void*)qkv_gemm,
                      hipFuncAttributeMaxDynamicSharedMemorySize, 147456);
  qkv_gemm<<<768, 512, 147456, stream>>>(actb, wb, qb, kb, vb, Qh, Kh, Vth);

  attn_kernel<<<1024, 256, 0, stream>>>(Qh, Kh, Vth, (float*)d_out);
}

// Round 14
// 129.190 us; speedup vs baseline: 1.0052x; 1.0052x over previous
//
#include <hip/hip_runtime.h>
#include <cstdint>
#include <cstddef>

#define B_   8
#define S_   1024
#define H_   1024
#define NH_  16
#define HD_  64
#define M_   8192   // B*S
#define N3_  3072   // 3*H
#define K_   1024

typedef __attribute__((ext_vector_type(8))) short bf16x8;
typedef __attribute__((ext_vector_type(4))) float f32x4;
typedef __attribute__((ext_vector_type(16))) float f32x16;
typedef __attribute__((ext_vector_type(8))) unsigned short u16x8;
typedef __attribute__((ext_vector_type(4))) unsigned u32x4;

__device__ __forceinline__ unsigned short f2bf(float f) {
  unsigned u = __builtin_bit_cast(unsigned, f);
  u += 0x7fffu + ((u >> 16) & 1u);      // round-to-nearest-even (finite inputs)
  return (unsigned short)(u >> 16);
}

__device__ __forceinline__ unsigned long long pack4bf(float a, float b,
                                                      float c, float d) {
  return (unsigned long long)f2bf(a)
       | ((unsigned long long)f2bf(b) << 16)
       | ((unsigned long long)f2bf(c) << 32)
       | ((unsigned long long)f2bf(d) << 48);
}

// one-instruction bf16-pair pack (RNE), T12 recipe
__device__ __forceinline__ unsigned cvtpk(float a, float b) {
  unsigned r;
  asm("v_cvt_pk_bf16_f32 %0, %1, %2" : "=v"(r) : "v"(a), "v"(b));
  return r;
}

// ---------------- fp32 -> bf16 pack ----------------
__global__ void cvt_kernel(const float* __restrict__ src,
                           unsigned short* __restrict__ dst, int n) {
  const int stride = gridDim.x * blockDim.x * 8;
  for (int i = (blockIdx.x * blockDim.x + threadIdx.x) * 8; i < n; i += stride) {
    float4 a = *reinterpret_cast<const float4*>(src + i);
    float4 b = *reinterpret_cast<const float4*>(src + i + 4);
    u16x8 o;
    o[0] = f2bf(a.x); o[1] = f2bf(a.y); o[2] = f2bf(a.z); o[3] = f2bf(a.w);
    o[4] = f2bf(b.x); o[5] = f2bf(b.y); o[6] = f2bf(b.z); o[7] = f2bf(b.w);
    *reinterpret_cast<u16x8*>(dst + i) = o;
  }
}

// fused q/k/v weight cvt (one launch): dst = [qw|kw|vw] bf16
__global__ void wcvt_kernel(const float* __restrict__ q,
                            const float* __restrict__ k,
                            const float* __restrict__ v,
                            unsigned short* __restrict__ dst) {
  const int i = (blockIdx.x * blockDim.x + threadIdx.x) * 8;   // < 3M
  const float* src;
  int off;
  if (i < 1048576)      { src = q; off = i; }
  else if (i < 2097152) { src = k; off = i - 1048576; }
  else                  { src = v; off = i - 2097152; }
  float4 a = *reinterpret_cast<const float4*>(src + off);
  float4 b = *reinterpret_cast<const float4*>(src + off + 4);
  u16x8 o;
  o[0] = f2bf(a.x); o[1] = f2bf(a.y); o[2] = f2bf(a.z); o[3] = f2bf(a.w);
  o[4] = f2bf(b.x); o[5] = f2bf(b.y); o[6] = f2bf(b.z); o[7] = f2bf(b.w);
  *reinterpret_cast<u16x8*>(dst + i) = o;
}

// ---------------- fused QKV GEMM: 128x128, BK=64, T3 2-phase + L2 supertile --
// (round-12 verified best: 68us, FETCH 49MB) 256 thr = 4 waves (2x2),
// 64x64/wave. Double-buffered 64KB LDS (2 blocks/CU). STAGE(kt+1) FIRST,
// then frag-reads+MFMA on buf[kt], ONE __syncthreads. L2 supertile: per XCD
// c = g*64 + m*8 + n -> A window 2MB + B window 2MB = 4MB = one L2.
__global__ __launch_bounds__(256, 2) void qkv_gemm(
    const unsigned short* __restrict__ A,    // [8192][1024] bf16
    const unsigned short* __restrict__ Bw,   // [3072][1024] bf16 (qw|kw|vw rows)
    const float* __restrict__ qb, const float* __restrict__ kb,
    const float* __restrict__ vb,
    unsigned short* __restrict__ Qh,   // [128][1024][64], pre-scaled by log2e/32
    unsigned short* __restrict__ Kh,   // [128][1024][64]
    unsigned short* __restrict__ Vth)  // [128][16 kt][64 hd][64 k]
{
  extern __shared__ char sm[];            // 64 KiB: buf[2] x (A 16K | B 16K)
  const int t = threadIdx.x;
  const int lane = t & 63;
  const int wm = t >> 7, wn = (t >> 6) & 1;

  // L2 supertile decomposition
  const int bid = blockIdx.x;             // 0..1535
  const int c = bid >> 3;                 // 0..191
  const int g = c >> 6;                   // 0..2  (bn group of 8 = one tensor)
  const int m = (c >> 3) & 7;             // 0..7
  const int n = c & 7;                    // 0..7
  const int bm = (bid & 7) * 8 + m;       // 0..63
  const int bn = g * 8 + n;               // 0..23

  const char* Ab = (const char*)A + (size_t)bm * 128 * 2048;
  const char* Bb = (const char*)Bw + (size_t)bn * 128 * 2048;

  f32x4 acc[4][4] = {};

  // stage 16KB A-half + 16KB B-half of K-slice kt into buffer `buf`
  #define STG(kt, buf)                                                         \
    { char* Ld = sm + (buf) * 32768;                                           \
      _Pragma("unroll")                                                        \
      for (int i = 0; i < 4; ++i) {                                            \
        const int off = (i * 256 + t) * 16;                                    \
        const int row = off >> 7;                                              \
        const int sc  = ((off >> 4) & 7) ^ (row & 7);                          \
        __builtin_amdgcn_global_load_lds(                                      \
          (const __attribute__((address_space(1))) void*)(Ab + (size_t)row * 2048 + (kt) * 128 + sc * 16), \
          (__attribute__((address_space(3))) void*)(Ld + off), 16, 0, 0);      \
        __builtin_amdgcn_global_load_lds(                                      \
          (const __attribute__((address_space(1))) void*)(Bb + (size_t)row * 2048 + (kt) * 128 + sc * 16), \
          (__attribute__((address_space(3))) void*)(Ld + 16384 + off), 16, 0, 0); \
      } }

  // prologue: stage tile 0, drain, barrier
  STG(0, 0)
  __syncthreads();

  for (int kt = 0; kt < 16; ++kt) {
    if (kt < 15) STG(kt + 1, (kt + 1) & 1)        // T3: issue next-tile FIRST
    const char* Acur = sm + (kt & 1) * 32768;
    const char* Bcur = Acur + 16384;
    #pragma unroll
    for (int kk = 0; kk < 2; ++kk) {
      bf16x8 af[4], bf[4];
      #pragma unroll
      for (int mb = 0; mb < 4; ++mb) {
        const int row = wm * 64 + mb * 16 + (lane & 15);
        const int j   = kk * 4 + (lane >> 4);
        af[mb] = *(const bf16x8*)(Acur + row * 128 + ((j ^ (row & 7)) << 4));
      }
      #pragma unroll
      for (int nb = 0; nb < 4; ++nb) {
        const int row = wn * 64 + nb * 16 + (lane & 15);
        const int j   = kk * 4 + (lane >> 4);
        bf[nb] = *(const bf16x8*)(Bcur + row * 128 + ((j ^ (row & 7)) << 4));
      }
      __builtin_amdgcn_s_setprio(1);
      #pragma unroll
      for (int mb = 0; mb < 4; ++mb)
        #pragma unroll
        for (int nb = 0; nb < 4; ++nb)
          acc[mb][nb] = __builtin_amdgcn_mfma_f32_16x16x32_bf16(
              af[mb], bf[nb], acc[mb][nb], 0, 0, 0);
      __builtin_amdgcn_s_setprio(0);
    }
    __syncthreads();   // one barrier/iter; drains this iter's 8 stage loads
  }

  // ---------------- coalesced epilogue through LDS (reuse sm[0..32K)) -------
  const int tensor = bn >> 3;             // block-uniform: 0=q 1=k 2=v
  const float scl = (tensor == 0) ? 0.04508422f : 1.0f;  // log2e/sqrt(1024)
  const float* bias = (tensor == 0) ? qb : (tensor == 1) ? kb : vb;
  char* E = sm;
  const int bloc = bm >> 3;               // batch b
  const int srow = (bm & 7) * 128;        // s base of tile

  if (tensor < 2) {
    // row-major [row 128][col 128] bf16, chunk-swizzled
    #pragma unroll
    for (int nb = 0; nb < 4; ++nb) {
      const int col = wn * 64 + nb * 16 + (lane & 15);
      const float bv = bias[(bn & 7) * 128 + col];
      #pragma unroll
      for (int mb = 0; mb < 4; ++mb) {
        #pragma unroll
        for (int r = 0; r < 4; ++r) {
          const int row = wm * 64 + mb * 16 + (lane >> 4) * 4 + r;
          const int byo = row * 256 + ((((col >> 3) ^ (row & 7)) << 4) | ((col & 7) << 1));
          *(unsigned short*)(E + byo) = f2bf((acc[mb][nb][r] + bv) * scl);
        }
      }
    }
    __syncthreads();
    unsigned short* dst = (tensor == 0) ? Qh : Kh;
    #pragma unroll
    for (int cch = 0; cch < 8; ++cch) {
      const int o = t * 128 + cch * 16;
      const int row = o >> 8;
      const int colb = o & 255;           // byte-in-row, 16B aligned
      const int col = colb >> 1;
      u32x4 v = *(const u32x4*)(E + row * 256 + ((((colb >> 4) ^ (row & 7)) << 4)));
      const int sg = srow + row;
      const int nhh = (bn & 7) * 2 + (col >> 6);
      const size_t db = ((size_t)(bloc * NH_ + nhh) * S_ + sg) * 128 + (col & 63) * 2;
      *(u32x4*)((char*)dst + db) = v;
    }
  } else {
    // transposed [col 128][row 128] bf16; r-quads pack to b64
    #pragma unroll
    for (int nb = 0; nb < 4; ++nb) {
      const int col = wn * 64 + nb * 16 + (lane & 15);
      const float bv = bias[(bn & 7) * 128 + col];
      #pragma unroll
      for (int mb = 0; mb < 4; ++mb) {
        const int row0 = wm * 64 + mb * 16 + (lane >> 4) * 4;
        unsigned long long w = pack4bf(acc[mb][nb][0] + bv, acc[mb][nb][1] + bv,
                                       acc[mb][nb][2] + bv, acc[mb][nb][3] + bv);
        const int byo = col * 256 + ((((row0 >> 3) ^ (col & 7)) << 4) | ((row0 & 7) << 1));
        *(unsigned long long*)(E + byo) = w;
      }
    }
    __syncthreads();
    #pragma unroll
    for (int cch = 0; cch < 8; ++cch) {
      const int o = t * 128 + cch * 16;
      const int col = o >> 8;
      const int rowb = o & 255;           // byte-in-col, 16B aligned
      const int row0 = rowb >> 1;         // 8 consecutive rows
      u32x4 v = *(const u32x4*)(E + col * 256 + ((((rowb >> 4) ^ (col & 7)) << 4)));
      const int sg0 = srow + row0;
      const int nhh = (bn & 7) * 2 + (col >> 6);
      const size_t db = (size_t)(bloc * NH_ + nhh) * 131072 +
                        (size_t)(sg0 >> 6) * 8192 + (col & 63) * 128 + (sg0 & 63) * 2;
      *(u32x4*)((char*)Vth + db) = v;
    }
  }
}

// ---- build PV A-frag for one 16-k step from 8 consecutive P regs ----
__device__ __forceinline__ bf16x8 mk_frag(const f32x16& s, const int base) {
  unsigned a0 = cvtpk(s[base + 0], s[base + 1]);
  unsigned a1 = cvtpk(s[base + 2], s[base + 3]);
  unsigned b0 = cvtpk(s[base + 4], s[base + 5]);
  unsigned b1 = cvtpk(s[base + 6], s[base + 7]);
  asm("v_permlane32_swap_b32 %0, %1" : "+v"(a0), "+v"(b0));
  asm("v_permlane32_swap_b32 %0, %1" : "+v"(a1), "+v"(b1));
  u32x4 u = {a0, a1, b0, b1};
  return __builtin_bit_cast(bf16x8, u);
}

// ------- flash attention: 8 waves / 256 q-rows per block, LDS-staged K/V -----
// Per-wave code identical to round-9; staging per head now paid 4x (not 8x),
// barriers amortize over 2x MFMA, grid 512 = exactly 2 blocks/CU (no tail).
__global__ __launch_bounds__(512, 4) void attn_kernel(
    const unsigned short* __restrict__ Qh,
    const unsigned short* __restrict__ Kh,
    const unsigned short* __restrict__ Vth,
    float* __restrict__ Out)
{
  __shared__ char smx[2][16384];   // [buf][ K 8KB | V 8KB ]
  const int t = threadIdx.x;       // 0..511
  const int lane = t & 63;
  const int wave = t >> 6;         // 0..7
  const int l31 = lane & 31;
  const int hi = lane >> 5;
  const int hw = blockIdx.x;              // 0..511
  const int xcd = hw & 7;
  const int rest = hw >> 3;               // 0..63
  const int qt = rest & 3;                // 0..3 (256-row q tiles)
  const int bh = (rest >> 2) * 8 + xcd;   // 0..127; 16 heads/XCD
  const int b = bh >> 4, nh = bh & 15;

  const unsigned short* Qp = Qh + (size_t)bh * (S_ * HD_);
  const char* Kp = (const char*)Kh + (size_t)bh * 131072;
  const char* Vp = (const char*)Vth + (size_t)bh * 131072;
  const int q0 = qt * 256 + wave * 32;

  bf16x8 bq[4];
  #pragma unroll
  for (int st = 0; st < 4; ++st)
    bq[st] = *reinterpret_cast<const bf16x8*>(
        Qp + (size_t)(q0 + l31) * HD_ + st * 16 + hi * 8);

  // 512 threads x 16B = one 8KB tile per call
  #define STAGE_TILE(dstbase, srcbase)                                            \
    { const int off = t * 16;                                                     \
      const int row = off >> 7;                                                   \
      const int sc  = ((off >> 4) & 7) ^ (row & 7);                               \
      __builtin_amdgcn_global_load_lds(                                           \
          (const __attribute__((address_space(1))) void*)((srcbase) + row * 128 + sc * 16), \
          (__attribute__((address_space(3))) void*)((dstbase) + off), 16, 0, 0);  \
    }

  STAGE_TILE(&smx[0][0],    Kp)
  STAGE_TILE(&smx[0][8192], Vp)
  __syncthreads();

  f32x16 o0 = {}, o1 = {};
  float lsum = 0.f;
  const int swr = l31 & 7;

  for (int kt = 0; kt < 16; ++kt) {
    const int cur = kt & 1;
    if (kt < 15) {
      STAGE_TILE(&smx[cur ^ 1][0],    Kp + (kt + 1) * 8192)
      STAGE_TILE(&smx[cur ^ 1][8192], Vp + (kt + 1) * 8192)
    }
    const char* Kb = &smx[cur][0];
    const char* Vb = &smx[cur][8192];

    f32x16 s0 = {}, s1 = {};
    #pragma unroll
    for (int st = 0; st < 4; ++st) {
      const int c = ((st * 2 + hi) ^ swr) << 4;
      bf16x8 ka = *reinterpret_cast<const bf16x8*>(Kb + l31 * 128 + c);
      bf16x8 kc = *reinterpret_cast<const bf16x8*>(Kb + (l31 + 32) * 128 + c);
      s0 = __builtin_amdgcn_mfma_f32_32x32x16_bf16(ka, bq[st], s0, 0, 0, 0);
      s1 = __builtin_amdgcn_mfma_f32_32x32x16_bf16(kc, bq[st], s1, 0, 0, 0);
    }

    bf16x8 va[4];
    #pragma unroll
    for (int ks = 0; ks < 2; ++ks) {
      const int c = ((ks * 2 + hi) ^ swr) << 4;
      va[ks * 2]     = *reinterpret_cast<const bf16x8*>(Vb + l31 * 128 + c);
      va[ks * 2 + 1] = *reinterpret_cast<const bf16x8*>(Vb + (l31 + 32) * 128 + c);
    }
    #pragma unroll
    for (int r = 0; r < 16; ++r) {
      s0[r] = __builtin_amdgcn_exp2f(s0[r]);
      lsum += s0[r];
    }
    bf16x8 f0 = mk_frag(s0, 0);
    bf16x8 f1 = mk_frag(s0, 8);
    o0 = __builtin_amdgcn_mfma_f32_32x32x16_bf16(f0, va[0], o0, 0, 0, 0);
    o1 = __builtin_amdgcn_mfma_f32_32x32x16_bf16(f0, va[1], o1, 0, 0, 0);
    o0 = __builtin_amdgcn_mfma_f32_32x32x16_bf16(f1, va[2], o0, 0, 0, 0);
    o1 = __builtin_amdgcn_mfma_f32_32x32x16_bf16(f1, va[3], o1, 0, 0, 0);

    #pragma unroll
    for (int ks = 0; ks < 2; ++ks) {
      const int c = (((ks + 2) * 2 + hi) ^ swr) << 4;
      va[ks * 2]     = *reinterpret_cast<const bf16x8*>(Vb + l31 * 128 + c);
      va[ks * 2 + 1] = *reinterpret_cast<const bf16x8*>(Vb + (l31 + 32) * 128 + c);
    }
    #pragma unroll
    for (int r = 0; r < 16; ++r) {
      s1[r] = __builtin_amdgcn_exp2f(s1[r]);
      lsum += s1[r];
    }
    bf16x8 f2 = mk_frag(s1, 0);
    bf16x8 f3 = mk_frag(s1, 8);
    o0 = __builtin_amdgcn_mfma_f32_32x32x16_bf16(f2, va[0], o0, 0, 0, 0);
    o1 = __builtin_amdgcn_mfma_f32_32x32x16_bf16(f2, va[1], o1, 0, 0, 0);
    o0 = __builtin_amdgcn_mfma_f32_32x32x16_bf16(f3, va[2], o0, 0, 0, 0);
    o1 = __builtin_amdgcn_mfma_f32_32x32x16_bf16(f3, va[3], o1, 0, 0, 0);

    __syncthreads();
  }

  const float ltot = lsum + __shfl_xor(lsum, 32);
  const float inv = 1.0f / ltot;
  #pragma unroll
  for (int r = 0; r < 16; ++r) {
    const int crow = (r & 3) + 8 * (r >> 2) + 4 * hi;
    const float invq = __shfl(inv, crow);
    float* op = Out + ((size_t)(b * S_ + q0 + crow)) * H_ + nh * HD_ + l31;
    op[0]  = o0[r] * invq;
    op[32] = o1[r] * invq;
  }
}

extern "C" void kernel_launch(void* const* d_in, const int* in_sizes, int n_in,
                              void* d_out, int out_size, void* d_ws, size_t ws_size,
                              hipStream_t stream) {
  const float* act = (const float*)d_in[0];
  const float* qw  = (const float*)d_in[1];
  const float* qb  = (const float*)d_in[2];
  const float* kw  = (const float*)d_in[3];
  const float* kb  = (const float*)d_in[4];
  const float* vw  = (const float*)d_in[5];
  const float* vb  = (const float*)d_in[6];

  char* ws = (char*)d_ws;
  unsigned short* actb = (unsigned short*)ws;                         // 16 MB
  unsigned short* wb   = (unsigned short*)(ws + 16777216);            // 6 MB
  unsigned short* Qh   = (unsigned short*)(ws + 23068672);            // 16 MB
  unsigned short* Kh   = Qh + 8388608;                                // 16 MB
  unsigned short* Vth  = Kh + 8388608;                                // 16 MB

  cvt_kernel<<<4096, 256, 0, stream>>>(act, actb, M_ * K_);
  wcvt_kernel<<<1536, 256, 0, stream>>>(qw, kw, vw, wb);

  hipFuncSetAttribute((const void*)qkv_gemm,
                      hipFuncAttributeMaxDynamicSharedMemorySize, 65536);
  qkv_gemm<<<1536, 256, 65536, stream>>>(actb, wb, qb, kb, vb, Qh, Kh, Vth);

  attn_kernel<<<512, 512, 0, stream>>>(Qh, Kh, Vth, (float*)d_out);
}

// Round 15
// 122.536 us; speedup vs baseline: 1.0598x; 1.0543x over previous
//
#include <hip/hip_runtime.h>
#include <cstdint>
#include <cstddef>

#define B_   8
#define S_   1024
#define H_   1024
#define NH_  16
#define HD_  64
#define M_   8192   // B*S
#define N3_  3072   // 3*H
#define K_   1024

typedef __attribute__((ext_vector_type(8))) short bf16x8;
typedef __attribute__((ext_vector_type(4))) float f32x4;
typedef __attribute__((ext_vector_type(16))) float f32x16;
typedef __attribute__((ext_vector_type(8))) unsigned short u16x8;
typedef __attribute__((ext_vector_type(4))) unsigned u32x4;

__device__ __forceinline__ unsigned short f2bf(float f) {
  unsigned u = __builtin_bit_cast(unsigned, f);
  u += 0x7fffu + ((u >> 16) & 1u);      // round-to-nearest-even (finite inputs)
  return (unsigned short)(u >> 16);
}

__device__ __forceinline__ unsigned long long pack4bf(float a, float b,
                                                      float c, float d) {
  return (unsigned long long)f2bf(a)
       | ((unsigned long long)f2bf(b) << 16)
       | ((unsigned long long)f2bf(c) << 32)
       | ((unsigned long long)f2bf(d) << 48);
}

// one-instruction bf16-pair pack (RNE), T12 recipe
__device__ __forceinline__ unsigned cvtpk(float a, float b) {
  unsigned r;
  asm("v_cvt_pk_bf16_f32 %0, %1, %2" : "=v"(r) : "v"(a), "v"(b));
  return r;
}

// ---------------- fp32 -> bf16 pack ----------------
__global__ void cvt_kernel(const float* __restrict__ src,
                           unsigned short* __restrict__ dst, int n) {
  const int stride = gridDim.x * blockDim.x * 8;
  for (int i = (blockIdx.x * blockDim.x + threadIdx.x) * 8; i < n; i += stride) {
    float4 a = *reinterpret_cast<const float4*>(src + i);
    float4 b = *reinterpret_cast<const float4*>(src + i + 4);
    u16x8 o;
    o[0] = f2bf(a.x); o[1] = f2bf(a.y); o[2] = f2bf(a.z); o[3] = f2bf(a.w);
    o[4] = f2bf(b.x); o[5] = f2bf(b.y); o[6] = f2bf(b.z); o[7] = f2bf(b.w);
    *reinterpret_cast<u16x8*>(dst + i) = o;
  }
}

// fused q/k/v weight cvt (one launch): dst = [qw|kw|vw] bf16
__global__ void wcvt_kernel(const float* __restrict__ q,
                            const float* __restrict__ k,
                            const float* __restrict__ v,
                            unsigned short* __restrict__ dst) {
  const int i = (blockIdx.x * blockDim.x + threadIdx.x) * 8;   // < 3M
  const float* src;
  int off;
  if (i < 1048576)      { src = q; off = i; }
  else if (i < 2097152) { src = k; off = i - 1048576; }
  else                  { src = v; off = i - 2097152; }
  float4 a = *reinterpret_cast<const float4*>(src + off);
  float4 b = *reinterpret_cast<const float4*>(src + off + 4);
  u16x8 o;
  o[0] = f2bf(a.x); o[1] = f2bf(a.y); o[2] = f2bf(a.z); o[3] = f2bf(a.w);
  o[4] = f2bf(b.x); o[5] = f2bf(b.y); o[6] = f2bf(b.z); o[7] = f2bf(b.w);
  *reinterpret_cast<u16x8*>(dst + i) = o;
}

// ---------------- fused QKV GEMM: 128x128, BK=64, T3 2-phase + L2 supertile --
// (round-12 verified best: 68us, FETCH 49MB) 256 thr = 4 waves (2x2),
// 64x64/wave. Double-buffered 64KB LDS (2 blocks/CU). STAGE(kt+1) FIRST,
// then frag-reads+MFMA on buf[kt], ONE __syncthreads. L2 supertile: per XCD
// c = g*64 + m*8 + n -> A window 2MB + B window 2MB = 4MB = one L2.
__global__ __launch_bounds__(256, 2) void qkv_gemm(
    const unsigned short* __restrict__ A,    // [8192][1024] bf16
    const unsigned short* __restrict__ Bw,   // [3072][1024] bf16 (qw|kw|vw rows)
    const float* __restrict__ qb, const float* __restrict__ kb,
    const float* __restrict__ vb,
    unsigned short* __restrict__ Qh,   // [128][1024][64], pre-scaled by log2e/32
    unsigned short* __restrict__ Kh,   // [128][1024][64]
    unsigned short* __restrict__ Vth)  // [128][16 kt][64 hd][64 k]
{
  extern __shared__ char sm[];            // 64 KiB: buf[2] x (A 16K | B 16K)
  const int t = threadIdx.x;
  const int lane = t & 63;
  const int wm = t >> 7, wn = (t >> 6) & 1;

  // L2 supertile decomposition
  const int bid = blockIdx.x;             // 0..1535
  const int c = bid >> 3;                 // 0..191
  const int g = c >> 6;                   // 0..2  (bn group of 8 = one tensor)
  const int m = (c >> 3) & 7;             // 0..7
  const int n = c & 7;                    // 0..7
  const int bm = (bid & 7) * 8 + m;       // 0..63
  const int bn = g * 8 + n;               // 0..23

  const char* Ab = (const char*)A + (size_t)bm * 128 * 2048;
  const char* Bb = (const char*)Bw + (size_t)bn * 128 * 2048;

  f32x4 acc[4][4] = {};

  // stage 16KB A-half + 16KB B-half of K-slice kt into buffer `buf`
  #define STG(kt, buf)                                                         \
    { char* Ld = sm + (buf) * 32768;                                           \
      _Pragma("unroll")                                                        \
      for (int i = 0; i < 4; ++i) {                                            \
        const int off = (i * 256 + t) * 16;                                    \
        const int row = off >> 7;                                              \
        const int sc  = ((off >> 4) & 7) ^ (row & 7);                          \
        __builtin_amdgcn_global_load_lds(                                      \
          (const __attribute__((address_space(1))) void*)(Ab + (size_t)row * 2048 + (kt) * 128 + sc * 16), \
          (__attribute__((address_space(3))) void*)(Ld + off), 16, 0, 0);      \
        __builtin_amdgcn_global_load_lds(                                      \
          (const __attribute__((address_space(1))) void*)(Bb + (size_t)row * 2048 + (kt) * 128 + sc * 16), \
          (__attribute__((address_space(3))) void*)(Ld + 16384 + off), 16, 0, 0); \
      } }

  // prologue: stage tile 0, drain, barrier
  STG(0, 0)
  __syncthreads();

  for (int kt = 0; kt < 16; ++kt) {
    if (kt < 15) STG(kt + 1, (kt + 1) & 1)        // T3: issue next-tile FIRST
    const char* Acur = sm + (kt & 1) * 32768;
    const char* Bcur = Acur + 16384;
    #pragma unroll
    for (int kk = 0; kk < 2; ++kk) {
      bf16x8 af[4], bf[4];
      #pragma unroll
      for (int mb = 0; mb < 4; ++mb) {
        const int row = wm * 64 + mb * 16 + (lane & 15);
        const int j   = kk * 4 + (lane >> 4);
        af[mb] = *(const bf16x8*)(Acur + row * 128 + ((j ^ (row & 7)) << 4));
      }
      #pragma unroll
      for (int nb = 0; nb < 4; ++nb) {
        const int row = wn * 64 + nb * 16 + (lane & 15);
        const int j   = kk * 4 + (lane >> 4);
        bf[nb] = *(const bf16x8*)(Bcur + row * 128 + ((j ^ (row & 7)) << 4));
      }
      __builtin_amdgcn_s_setprio(1);
      #pragma unroll
      for (int mb = 0; mb < 4; ++mb)
        #pragma unroll
        for (int nb = 0; nb < 4; ++nb)
          acc[mb][nb] = __builtin_amdgcn_mfma_f32_16x16x32_bf16(
              af[mb], bf[nb], acc[mb][nb], 0, 0, 0);
      __builtin_amdgcn_s_setprio(0);
    }
    __syncthreads();   // one barrier/iter; drains this iter's 8 stage loads
  }

  // ---------------- coalesced epilogue through LDS (reuse sm[0..32K)) -------
  const int tensor = bn >> 3;             // block-uniform: 0=q 1=k 2=v
  const float scl = (tensor == 0) ? 0.04508422f : 1.0f;  // log2e/sqrt(1024)
  const float* bias = (tensor == 0) ? qb : (tensor == 1) ? kb : vb;
  char* E = sm;
  const int bloc = bm >> 3;               // batch b
  const int srow = (bm & 7) * 128;        // s base of tile

  if (tensor < 2) {
    // row-major [row 128][col 128] bf16, chunk-swizzled
    #pragma unroll
    for (int nb = 0; nb < 4; ++nb) {
      const int col = wn * 64 + nb * 16 + (lane & 15);
      const float bv = bias[(bn & 7) * 128 + col];
      #pragma unroll
      for (int mb = 0; mb < 4; ++mb) {
        #pragma unroll
        for (int r = 0; r < 4; ++r) {
          const int row = wm * 64 + mb * 16 + (lane >> 4) * 4 + r;
          const int byo = row * 256 + ((((col >> 3) ^ (row & 7)) << 4) | ((col & 7) << 1));
          *(unsigned short*)(E + byo) = f2bf((acc[mb][nb][r] + bv) * scl);
        }
      }
    }
    __syncthreads();
    unsigned short* dst = (tensor == 0) ? Qh : Kh;
    #pragma unroll
    for (int cch = 0; cch < 8; ++cch) {
      const int o = t * 128 + cch * 16;
      const int row = o >> 8;
      const int colb = o & 255;           // byte-in-row, 16B aligned
      const int col = colb >> 1;
      u32x4 v = *(const u32x4*)(E + row * 256 + ((((colb >> 4) ^ (row & 7)) << 4)));
      const int sg = srow + row;
      const int nhh = (bn & 7) * 2 + (col >> 6);
      const size_t db = ((size_t)(bloc * NH_ + nhh) * S_ + sg) * 128 + (col & 63) * 2;
      *(u32x4*)((char*)dst + db) = v;
    }
  } else {
    // transposed [col 128][row 128] bf16; r-quads pack to b64
    #pragma unroll
    for (int nb = 0; nb < 4; ++nb) {
      const int col = wn * 64 + nb * 16 + (lane & 15);
      const float bv = bias[(bn & 7) * 128 + col];
      #pragma unroll
      for (int mb = 0; mb < 4; ++mb) {
        const int row0 = wm * 64 + mb * 16 + (lane >> 4) * 4;
        unsigned long long w = pack4bf(acc[mb][nb][0] + bv, acc[mb][nb][1] + bv,
                                       acc[mb][nb][2] + bv, acc[mb][nb][3] + bv);
        const int byo = col * 256 + ((((row0 >> 3) ^ (col & 7)) << 4) | ((row0 & 7) << 1));
        *(unsigned long long*)(E + byo) = w;
      }
    }
    __syncthreads();
    #pragma unroll
    for (int cch = 0; cch < 8; ++cch) {
      const int o = t * 128 + cch * 16;
      const int col = o >> 8;
      const int rowb = o & 255;           // byte-in-col, 16B aligned
      const int row0 = rowb >> 1;         // 8 consecutive rows
      u32x4 v = *(const u32x4*)(E + col * 256 + ((((rowb >> 4) ^ (col & 7)) << 4)));
      const int sg0 = srow + row0;
      const int nhh = (bn & 7) * 2 + (col >> 6);
      const size_t db = (size_t)(bloc * NH_ + nhh) * 131072 +
                        (size_t)(sg0 >> 6) * 8192 + (col & 63) * 128 + (sg0 & 63) * 2;
      *(u32x4*)((char*)Vth + db) = v;
    }
  }
}

// ---- build PV A-frag for one 16-k step from 8 consecutive P regs ----
__device__ __forceinline__ bf16x8 mk_frag(const f32x16& s, const int base) {
  unsigned a0 = cvtpk(s[base + 0], s[base + 1]);
  unsigned a1 = cvtpk(s[base + 2], s[base + 3]);
  unsigned b0 = cvtpk(s[base + 4], s[base + 5]);
  unsigned b1 = cvtpk(s[base + 6], s[base + 7]);
  asm("v_permlane32_swap_b32 %0, %1" : "+v"(a0), "+v"(b0));
  asm("v_permlane32_swap_b32 %0, %1" : "+v"(a1), "+v"(b1));
  u32x4 u = {a0, a1, b0, b1};
  return __builtin_bit_cast(bf16x8, u);
}

// ---------------- flash attention: LDS-staged K/V, double-buffered ----------------
// (round-9 best config: 4 waves, 3 blocks/CU, no setprio — best of 4 variants)
__global__ __launch_bounds__(256, 3) void attn_kernel(
    const unsigned short* __restrict__ Qh,
    const unsigned short* __restrict__ Kh,
    const unsigned short* __restrict__ Vth,
    float* __restrict__ Out)
{
  __shared__ char smx[2][16384];   // [buf][ K 8KB | V 8KB ]
  const int t = threadIdx.x;
  const int lane = t & 63;
  const int wave = t >> 6;
  const int l31 = lane & 31;
  const int hi = lane >> 5;
  const int hw = blockIdx.x;              // 0..1023
  const int xcd = hw & 7;
  const int qt = (hw >> 3) & 7;
  const int bh = (hw >> 6) * 8 + xcd;     // 0..127
  const int b = bh >> 4, nh = bh & 15;

  const unsigned short* Qp = Qh + (size_t)bh * (S_ * HD_);
  const char* Kp = (const char*)Kh + (size_t)bh * 131072;
  const char* Vp = (const char*)Vth + (size_t)bh * 131072;
  const int q0 = qt * 128 + wave * 32;

  bf16x8 bq[4];
  #pragma unroll
  for (int st = 0; st < 4; ++st)
    bq[st] = *reinterpret_cast<const bf16x8*>(
        Qp + (size_t)(q0 + l31) * HD_ + st * 16 + hi * 8);

  const int soff0 = wave * 1024 + lane * 16;
  #define STAGE_TILE(dstbase, srcbase)                                            \
    _Pragma("unroll")                                                             \
    for (int j = 0; j < 2; ++j) {                                                 \
      const int off = j * 4096 + soff0;                                           \
      const int row = off >> 7;                                                   \
      const int sc  = ((off >> 4) & 7) ^ (row & 7);                               \
      __builtin_amdgcn_global_load_lds(                                           \
          (const __attribute__((address_space(1))) void*)((srcbase) + row * 128 + sc * 16), \
          (__attribute__((address_space(3))) void*)((dstbase) + off), 16, 0, 0);  \
    }

  STAGE_TILE(&smx[0][0],    Kp)
  STAGE_TILE(&smx[0][8192], Vp)
  __syncthreads();

  f32x16 o0 = {}, o1 = {};
  float lsum = 0.f;
  const int swr = l31 & 7;

  for (int kt = 0; kt < 16; ++kt) {
    const int cur = kt & 1;
    if (kt < 15) {
      STAGE_TILE(&smx[cur ^ 1][0],    Kp + (kt + 1) * 8192)
      STAGE_TILE(&smx[cur ^ 1][8192], Vp + (kt + 1) * 8192)
    }
    const char* Kb = &smx[cur][0];
    const char* Vb = &smx[cur][8192];

    f32x16 s0 = {}, s1 = {};
    #pragma unroll
    for (int st = 0; st < 4; ++st) {
      const int c = ((st * 2 + hi) ^ swr) << 4;
      bf16x8 ka = *reinterpret_cast<const bf16x8*>(Kb + l31 * 128 + c);
      bf16x8 kc = *reinterpret_cast<const bf16x8*>(Kb + (l31 + 32) * 128 + c);
      s0 = __builtin_amdgcn_mfma_f32_32x32x16_bf16(ka, bq[st], s0, 0, 0, 0);
      s1 = __builtin_amdgcn_mfma_f32_32x32x16_bf16(kc, bq[st], s1, 0, 0, 0);
    }

    bf16x8 va[4];
    #pragma unroll
    for (int ks = 0; ks < 2; ++ks) {
      const int c = ((ks * 2 + hi) ^ swr) << 4;
      va[ks * 2]     = *reinterpret_cast<const bf16x8*>(Vb + l31 * 128 + c);
      va[ks * 2 + 1] = *reinterpret_cast<const bf16x8*>(Vb + (l31 + 32) * 128 + c);
    }
    #pragma unroll
    for (int r = 0; r < 16; ++r) {
      s0[r] = __builtin_amdgcn_exp2f(s0[r]);
      lsum += s0[r];
    }
    bf16x8 f0 = mk_frag(s0, 0);
    bf16x8 f1 = mk_frag(s0, 8);
    o0 = __builtin_amdgcn_mfma_f32_32x32x16_bf16(f0, va[0], o0, 0, 0, 0);
    o1 = __builtin_amdgcn_mfma_f32_32x32x16_bf16(f0, va[1], o1, 0, 0, 0);
    o0 = __builtin_amdgcn_mfma_f32_32x32x16_bf16(f1, va[2], o0, 0, 0, 0);
    o1 = __builtin_amdgcn_mfma_f32_32x32x16_bf16(f1, va[3], o1, 0, 0, 0);

    #pragma unroll
    for (int ks = 0; ks < 2; ++ks) {
      const int c = (((ks + 2) * 2 + hi) ^ swr) << 4;
      va[ks * 2]     = *reinterpret_cast<const bf16x8*>(Vb + l31 * 128 + c);
      va[ks * 2 + 1] = *reinterpret_cast<const bf16x8*>(Vb + (l31 + 32) * 128 + c);
    }
    #pragma unroll
    for (int r = 0; r < 16; ++r) {
      s1[r] = __builtin_amdgcn_exp2f(s1[r]);
      lsum += s1[r];
    }
    bf16x8 f2 = mk_frag(s1, 0);
    bf16x8 f3 = mk_frag(s1, 8);
    o0 = __builtin_amdgcn_mfma_f32_32x32x16_bf16(f2, va[0], o0, 0, 0, 0);
    o1 = __builtin_amdgcn_mfma_f32_32x32x16_bf16(f2, va[1], o1, 0, 0, 0);
    o0 = __builtin_amdgcn_mfma_f32_32x32x16_bf16(f3, va[2], o0, 0, 0, 0);
    o1 = __builtin_amdgcn_mfma_f32_32x32x16_bf16(f3, va[3], o1, 0, 0, 0);

    __syncthreads();
  }

  const float ltot = lsum + __shfl_xor(lsum, 32);
  const float inv = 1.0f / ltot;
  #pragma unroll
  for (int r = 0; r < 16; ++r) {
    const int crow = (r & 3) + 8 * (r >> 2) + 4 * hi;
    const float invq = __shfl(inv, crow);
    float* op = Out + ((size_t)(b * S_ + q0 + crow)) * H_ + nh * HD_ + l31;
    op[0]  = o0[r] * invq;
    op[32] = o1[r] * invq;
  }
}

extern "C" void kernel_launch(void* const* d_in, const int* in_sizes, int n_in,
                              void* d_out, int out_size, void* d_ws, size_t ws_size,
                              hipStream_t stream) {
  const float* act = (const float*)d_in[0];
  const float* qw  = (const float*)d_in[1];
  const float* qb  = (const float*)d_in[2];
  const float* kw  = (const float*)d_in[3];
  const float* kb  = (const float*)d_in[4];
  const float* vw  = (const float*)d_in[5];
  const float* vb  = (const float*)d_in[6];

  char* ws = (char*)d_ws;
  unsigned short* actb = (unsigned short*)ws;                         // 16 MB
  unsigned short* wb   = (unsigned short*)(ws + 16777216);            // 6 MB
  unsigned short* Qh   = (unsigned short*)(ws + 23068672);            // 16 MB
  unsigned short* Kh   = Qh + 8388608;                                // 16 MB
  unsigned short* Vth  = Kh + 8388608;                                // 16 MB

  cvt_kernel<<<4096, 256, 0, stream>>>(act, actb, M_ * K_);
  wcvt_kernel<<<1536, 256, 0, stream>>>(qw, kw, vw, wb);

  hipFuncSetAttribute((const void*)qkv_gemm,
                      hipFuncAttributeMaxDynamicSharedMemorySize, 65536);
  qkv_gemm<<<1536, 256, 65536, stream>>>(actb, wb, qb, kb, vb, Qh, Kh, Vth);

  attn_kernel<<<1024, 256, 0, stream>>>(Qh, Kh, Vth, (float*)d_out);
}